// Round 7
// baseline (348.728 us; speedup 1.0000x reference)
//
#include <hip/hip_runtime.h>
#include <hip/hip_bf16.h>
#include <stdint.h>

#define SS 8192
#define DD 1024
#define RR 16
#define OO 512

typedef __bf16 bf16_8 __attribute__((ext_vector_type(8)));
typedef float f32_4 __attribute__((ext_vector_type(4)));
typedef int i32_4 __attribute__((ext_vector_type(4)));

typedef __attribute__((address_space(1))) void g1_void;
typedef __attribute__((address_space(3))) void lds_void;

#define L2E 1.44269504f

__device__ __forceinline__ void gload_lds16(const void* g, void* l) {
  __builtin_amdgcn_global_load_lds((g1_void*)(uintptr_t)g,
                                   (lds_void*)(uint32_t)(uintptr_t)l, 16, 0, 0);
}

// Per-row absmax quantization to int8 + zero d_out.
// R7 wave-per-row version (PASSED R2-R6, absmax 0.0625). Byte-identical.
__global__ __launch_bounds__(256) void somfnn_quant(
    const float* __restrict__ X, const float* __restrict__ W,
    char* __restrict__ Xq, char* __restrict__ Wq,
    float* __restrict__ sX, float* __restrict__ sW, float4* __restrict__ out) {
  const int tid = threadIdx.x;
  const int wv = tid >> 6;
  const int l = tid & 63;
  const int r = blockIdx.x * 4 + wv;  // 0..16383; rows 0..8191 = X, rest = W
  const bool isX = r < SS;
  const float* src = isX ? (X + (size_t)r * DD) : (W + (size_t)(r - SS) * DD);
  char* dst = isX ? (Xq + (size_t)r * DD) : (Wq + (size_t)(r - SS) * DD);

  const float4* s4 = (const float4*)src;
  float4 v[4];
#pragma unroll
  for (int c = 0; c < 4; ++c) v[c] = s4[c * 64 + l];  // 1 KB/wave/instr, x4 in flight

  // zero 4 KB of out per block while the row loads are in flight
  out[(size_t)blockIdx.x * 256 + tid] = float4{0.f, 0.f, 0.f, 0.f};

  float m = 0.f;
#pragma unroll
  for (int c = 0; c < 4; ++c)
    m = fmaxf(m, fmaxf(fmaxf(fabsf(v[c].x), fabsf(v[c].y)),
                       fmaxf(fabsf(v[c].z), fabsf(v[c].w))));
#pragma unroll
  for (int off = 32; off > 0; off >>= 1) m = fmaxf(m, __shfl_xor(m, off, 64));
  m = fmaxf(m, 1e-20f);

  const float inv = 127.0f / m;
  int* di = (int*)dst;
#pragma unroll
  for (int c = 0; c < 4; ++c) {
    int q0 = __float2int_rn(v[c].x * inv);
    int q1 = __float2int_rn(v[c].y * inv);
    int q2 = __float2int_rn(v[c].z * inv);
    int q3 = __float2int_rn(v[c].w * inv);
    di[c * 64 + l] = (q0 & 0xff) | ((q1 & 0xff) << 8) | ((q2 & 0xff) << 16) |
                     ((q3 & 0xff) << 24);
  }
  if (l == 0) {
    if (isX) sX[r] = m / 127.0f;
    else sW[r - SS] = m / 127.0f;
  }
}

// i8 GEMM. R12: BARRIER-FREE MAIN LOOP (per-wave private LDS double buffer).
// Evidence across R0-R11: perf tracks MFMA-per-barrier (R0 32/barrier=102us;
// every 16/barrier variant 110-144us) independent of buffering, vmcnt
// discipline, or occupancy (R11: real 9 waves/CU still 117us). The ~1-2k cyc
// per-barrier tax is the 4-wave convoy (drain + skew) that 2 blocks/CU can't
// hide. Fix: waves share NOTHING in the main loop -> zero barriers.
//  - each wave owns 16 KB LDS: dbuf x (A 64x64 i8 + B 64x64 i8) for its own
//    64x64 output sub-tile; staged via global_load_lds (wave-uniform dest,
//    per-lane source), self-paced by per-wave counted vmcnt.
//  - iter t: wait vmcnt(8) [drains iter-t loads issued at t-2 ~800cyc ago],
//    ds_read frags, 16 MFMA, then lgkmcnt(0)+sched_barrier fence and issue
//    iter t+2 into the buffer just read. Last iter waits vmcnt(0).
//  - vmcnt exact: single post-init __syncthreads drains all init VMEM; the
//    loop's only VMEM = these 8 gloads/iter; atomics after loop.
//  - LDS slot map slot(r,kc)=(r>>2)*16+kc*4+(r&3), read chunk q^((r>>2)&3):
//    <=2-way bank aliasing on b128 frag reads (2-way free, m136).
// Staging issue traffic doubles (no sharing) but unique bytes/CU unchanged
// (L1/L2 absorb duplicates). LDS 64+12.5=78.3 KB = R0 footprint, 2 blk/CU.
__global__ __launch_bounds__(256, 2) void somfnn_gemm_i8(
    const char* __restrict__ Xq, const char* __restrict__ Wq,
    const float* __restrict__ sX, const float* __restrict__ sW,
    const float* __restrict__ bias_g, const float* __restrict__ lam_g,
    float* __restrict__ out) {
  constexpr int BM = 128, BN = 128;
  constexpr int NSTEP = 8 * 16;  // 8 rules x 16 k-tiles (K=64 each) = 128

  __shared__ __align__(16) char lds_t[4][2][8192];  // [wave][buf][A 4KB | B 4KB]
  __shared__ float lds_bias[8 * BN];   // -b * log2e, per rule (4 KB)
  __shared__ float lds_lam[8 * BM];    // 4 KB
  __shared__ float lds_sB[8 * BN];     // W-row scales (4 KB)
  __shared__ float lds_sA[BM];         // X-row scales (0.5 KB)

  const int tid = threadIdx.x;
  const int bid = blockIdx.x;

  const int l = tid & 63;
  const int w = tid >> 6;
  const int lane15 = l & 15;
  const int q = l >> 4;
  const int wm = w >> 1;   // 2x2 wave grid, each wave 64x64
  const int wn = w & 1;

  // L2-locality swizzle (R0 grid): XCD = bid%8 owns s-tiles [xcd*8, xcd*8+8)
  const int xcd = bid & 7;
  const int chunk = bid >> 3;            // [0,64)
  const int sb = xcd * 8 + (chunk & 7);  // A slice 1MB, L2-resident
  const int ob = (chunk >> 3) & 3;
  const int rhalf = chunk >> 5;
  const int s0 = sb * BM;
  const int o0 = ob * BN;
  const int r0 = rhalf * 8;

  for (int idx = tid; idx < 8 * BN; idx += 256) {
    int rr = idx >> 7, j = idx & 127;
    lds_bias[idx] = -L2E * bias_g[(r0 + rr) * OO + o0 + j];
    lds_sB[idx] = sW[(r0 + rr) * OO + o0 + j];
  }
  for (int idx = tid; idx < 8 * BM; idx += 256) {
    int rr = idx >> 7, i = idx & 127;
    lds_lam[idx] = lam_g[(s0 + i) * RR + (r0 + rr)];
  }
  if (tid < BM) lds_sA[tid] = sX[s0 + tid];

  // Per-lane global offsets for the wave's private 64x64 staging.
  // gload i writes LDS slots s = 64i + l (linear 1KB window). Inverse of the
  // slot map: r = ((s>>4)<<2)|(s&3), kc = ((s>>2)&3)^((s>>4)&3).
  int arow_off[4];
#pragma unroll
  for (int i = 0; i < 4; ++i) {
    int s = 64 * i + l;
    int r = ((s >> 4) << 2) | (s & 3);
    int kc = ((s >> 2) & 3) ^ ((s >> 4) & 3);
    arow_off[i] = r * DD + kc * 16;
  }

  // fragment LDS byte offsets: frag (t, q) reads rows r = t*16+lane15 at
  // slot(r, q^((r>>2)&3)) -> byte = (r>>2)*256 + (q^((r>>2)&3))*64 + (r&3)*16
  int afo[4];
#pragma unroll
  for (int t = 0; t < 4; ++t) {
    int r = t * 16 + lane15;
    afo[t] = (r >> 2) * 256 + ((q ^ ((r >> 2) & 3)) * 64) + ((r & 3) * 16);
  }

  const char* gAbase = Xq + (size_t)(s0 + wm * 64) * DD;
  const char* gBbase = Wq + ((size_t)r0 * OO + o0 + wn * 64) * DD;
  char* lds_w = &lds_t[w][0][0];

  auto issue = [&](int it, int buf) {
    int rl = it >> 4, kt = it & 15;
    const char* ga = gAbase + kt * 64;
    const char* gb = gBbase + (size_t)rl * OO * DD + kt * 64;
    char* la = lds_w + buf * 8192;
#pragma unroll
    for (int i = 0; i < 4; ++i) gload_lds16(ga + arow_off[i], la + i * 1024);
#pragma unroll
    for (int i = 0; i < 4; ++i) gload_lds16(gb + arow_off[i], la + 4096 + i * 1024);
  };

  i32_4 acc[4][4];
  f32_4 oacc[4][4];
#pragma unroll
  for (int mi = 0; mi < 4; ++mi)
#pragma unroll
    for (int ni = 0; ni < 4; ++ni) {
      acc[mi][ni] = i32_4{0, 0, 0, 0};
      oacc[mi][ni] = f32_4{0.f, 0.f, 0.f, 0.f};
    }

  __syncthreads();  // init fills visible to all waves; vmcnt/lgkm drained

  issue(0, 0);
  issue(1, 1);

  for (int it = 0; it < NSTEP; ++it) {
    const int cur = it & 1;

    // drain this iter's loads (issued 2 iters = ~800 cyc ago); keep the
    // next iter's 8 in flight. Per-wave count: loop VMEM = gloads only.
    if (it + 1 < NSTEP) {
      asm volatile("s_waitcnt vmcnt(8)" ::: "memory");
    } else {
      asm volatile("s_waitcnt vmcnt(0)" ::: "memory");
    }
    __builtin_amdgcn_sched_barrier(0);

    const char* A = lds_w + cur * 8192;
    i32_4 av[4], bv[4];
#pragma unroll
    for (int mi = 0; mi < 4; ++mi) av[mi] = *(const i32_4*)(A + afo[mi]);
#pragma unroll
    for (int ni = 0; ni < 4; ++ni) bv[ni] = *(const i32_4*)(A + 4096 + afo[ni]);
#pragma unroll
    for (int mi = 0; mi < 4; ++mi)
#pragma unroll
      for (int ni = 0; ni < 4; ++ni)
        acc[mi][ni] =
            __builtin_amdgcn_mfma_i32_16x16x64_i8(av[mi], bv[ni], acc[mi][ni], 0, 0, 0);

    if ((it & 15) == 15) {  // rule rl finished K: dequant + sigmoid + reduce
      const int rl = it >> 4;
      float lsa[4][4], lamv[4][4];
#pragma unroll
      for (int mi = 0; mi < 4; ++mi)
#pragma unroll
        for (int v = 0; v < 4; ++v) {
          int ridx = wm * 64 + mi * 16 + q * 4 + v;
          lsa[mi][v] = -L2E * lds_sA[ridx];
          lamv[mi][v] = lds_lam[rl * BM + ridx];
        }
#pragma unroll
      for (int ni = 0; ni < 4; ++ni) {
        const int cidx = wn * 64 + ni * 16 + lane15;
        const float nb = lds_bias[rl * BN + cidx];
        const float sbv = lds_sB[rl * BN + cidx];
#pragma unroll
        for (int mi = 0; mi < 4; ++mi)
#pragma unroll
          for (int v = 0; v < 4; ++v) {
            float t = __builtin_fmaf((float)acc[mi][ni][v], lsa[mi][v] * sbv, nb);
            float e = __builtin_amdgcn_exp2f(t);
            float h = __builtin_amdgcn_rcpf(1.0f + e);
            oacc[mi][ni][v] = __builtin_fmaf(lamv[mi][v], h, oacc[mi][ni][v]);
            acc[mi][ni][v] = 0;
          }
      }
    }

    if (it + 2 < NSTEP) {
      // frag regs already consumed by MFMAs -> lgkmcnt(0) is ~free; it
      // guarantees no in-flight ds_read targets the buffer we now overwrite.
      asm volatile("s_waitcnt lgkmcnt(0)" ::: "memory");
      __builtin_amdgcn_sched_barrier(0);
      issue(it + 2, cur);
    }
  }

#pragma unroll
  for (int mi = 0; mi < 4; ++mi)
#pragma unroll
    for (int ni = 0; ni < 4; ++ni)
#pragma unroll
      for (int v = 0; v < 4; ++v) {
        int row = s0 + wm * 64 + mi * 16 + q * 4 + v;
        int col = o0 + wn * 64 + ni * 16 + lane15;
        atomicAdd(&out[row * OO + col], oacc[mi][ni][v]);
      }
}

// Fallback (ws too small): bf16 GEMM converting fp32 during LDS staging.
__global__ __launch_bounds__(256, 2) void somfnn_gemm_fb(
    const float* __restrict__ Xf32, const float* __restrict__ Wf32,
    const float* __restrict__ bias_g, const float* __restrict__ lam_g,
    float* __restrict__ out) {
  constexpr int BM = 128, BN = 128, BK = 64;
  constexpr int TILE = BM * BK;
  constexpr int NSTEP = 8 * (DD / BK);

  __shared__ __align__(16) __bf16 lds_a[2][TILE];
  __shared__ __align__(16) __bf16 lds_b[2][TILE];
  __shared__ float lds_bias[8 * BN];
  __shared__ float lds_lam[8 * BM];

  const int tid = threadIdx.x;
  const int bid = blockIdx.x;
  const int l = tid & 63;
  const int w = tid >> 6;
  const int lane15 = l & 15;
  const int q = l >> 4;
  const int wm = w >> 1;
  const int wn = w & 1;

  const int xcd = bid & 7;
  const int chunk = bid >> 3;
  const int sb = xcd * 8 + (chunk & 7);
  const int ob = (chunk >> 3) & 3;
  const int rhalf = chunk >> 5;
  const int s0 = sb * BM;
  const int o0 = ob * BN;
  const int r0 = rhalf * 8;

  for (int idx = tid; idx < 8 * BN; idx += 256) {
    int rr = idx >> 7, j = idx & 127;
    lds_bias[idx] = -L2E * bias_g[(r0 + rr) * OO + o0 + j];
  }
  for (int idx = tid; idx < 8 * BM; idx += 256) {
    int rr = idx >> 7, i = idx & 127;
    lds_lam[idx] = lam_g[(s0 + i) * RR + (r0 + rr)];
  }

  int goffs[4], coffs[4];
#pragma unroll
  for (int i = 0; i < 4; ++i) {
    int c = (w * 4 + i) * 64 + l;
    int row = c >> 3;
    int k8 = (c & 7) ^ (row & 7);
    goffs[i] = row * DD + k8 * 8;
    coffs[i] = c * 8;
  }
  int afo[4], bfo[4];
#pragma unroll
  for (int t = 0; t < 4; ++t) {
    int ra = wm * 64 + t * 16 + lane15;
    afo[t] = (ra * 8 + (q ^ (ra & 7))) * 8;
    int rb = wn * 64 + t * 16 + lane15;
    bfo[t] = (rb * 8 + (q ^ (rb & 7))) * 8;
  }

  float4 ra_[4][2], rb_[4][2];
  auto issue_fb = [&](int step) {
    int rl = step >> 4, kt = step & 15;
    const float* ga = Xf32 + s0 * DD + kt * BK;
    const float* gb = Wf32 + ((r0 + rl) * OO + o0) * DD + kt * BK;
#pragma unroll
    for (int i = 0; i < 4; ++i) {
      const float4* p = (const float4*)(ga + goffs[i]);
      ra_[i][0] = p[0]; ra_[i][1] = p[1];
      const float4* pb = (const float4*)(gb + goffs[i]);
      rb_[i][0] = pb[0]; rb_[i][1] = pb[1];
    }
  };
  auto commit_fb = [&](int buf) {
#pragma unroll
    for (int i = 0; i < 4; ++i) {
      bf16_8 t;
      t[0] = (__bf16)ra_[i][0].x; t[1] = (__bf16)ra_[i][0].y;
      t[2] = (__bf16)ra_[i][0].z; t[3] = (__bf16)ra_[i][0].w;
      t[4] = (__bf16)ra_[i][1].x; t[5] = (__bf16)ra_[i][1].y;
      t[6] = (__bf16)ra_[i][1].z; t[7] = (__bf16)ra_[i][1].w;
      *(bf16_8*)&lds_a[buf][coffs[i]] = t;
      bf16_8 u;
      u[0] = (__bf16)rb_[i][0].x; u[1] = (__bf16)rb_[i][0].y;
      u[2] = (__bf16)rb_[i][0].z; u[3] = (__bf16)rb_[i][0].w;
      u[4] = (__bf16)rb_[i][1].x; u[5] = (__bf16)rb_[i][1].y;
      u[6] = (__bf16)rb_[i][1].z; u[7] = (__bf16)rb_[i][1].w;
      *(bf16_8*)&lds_b[buf][coffs[i]] = u;
    }
  };

  f32_4 acc[4][4], oacc[4][4];
#pragma unroll
  for (int mi = 0; mi < 4; ++mi)
#pragma unroll
    for (int ni = 0; ni < 4; ++ni) {
      acc[mi][ni] = f32_4{0.f, 0.f, 0.f, 0.f};
      oacc[mi][ni] = f32_4{0.f, 0.f, 0.f, 0.f};
    }

  issue_fb(0);
  commit_fb(0);
  __syncthreads();

  for (int step = 0; step < NSTEP; ++step) {
    const int cur = step & 1;
    const bool more = (step + 1) < NSTEP;
    if (more) issue_fb(step + 1);

    const __bf16* A = lds_a[cur];
    const __bf16* B = lds_b[cur];
#pragma unroll
    for (int ks = 0; ks < 2; ++ks) {
      const int xr = ks ? 32 : 0;
      bf16_8 av[4], bv[4];
#pragma unroll
      for (int mi = 0; mi < 4; ++mi) av[mi] = *(const bf16_8*)(A + (afo[mi] ^ xr));
#pragma unroll
      for (int ni = 0; ni < 4; ++ni) bv[ni] = *(const bf16_8*)(B + (bfo[ni] ^ xr));
#pragma unroll
      for (int mi = 0; mi < 4; ++mi)
#pragma unroll
        for (int ni = 0; ni < 4; ++ni)
          acc[mi][ni] =
              __builtin_amdgcn_mfma_f32_16x16x32_bf16(av[mi], bv[ni], acc[mi][ni], 0, 0, 0);
    }
    if (more) commit_fb(cur ^ 1);

    if ((step & 15) == 15) {
      const int rl = step >> 4;
      float lamv[4][4];
#pragma unroll
      for (int mi = 0; mi < 4; ++mi)
#pragma unroll
        for (int v = 0; v < 4; ++v)
          lamv[mi][v] = lds_lam[rl * BM + wm * 64 + mi * 16 + q * 4 + v];
#pragma unroll
      for (int ni = 0; ni < 4; ++ni) {
        const float nb = lds_bias[rl * BN + wn * 64 + ni * 16 + lane15];
#pragma unroll
        for (int mi = 0; mi < 4; ++mi)
#pragma unroll
          for (int v = 0; v < 4; ++v) {
            float t = __builtin_fmaf(acc[mi][ni][v], -L2E, nb);
            float e = __builtin_amdgcn_exp2f(t);
            float h = __builtin_amdgcn_rcpf(1.0f + e);
            oacc[mi][ni][v] = __builtin_fmaf(lamv[mi][v], h, oacc[mi][ni][v]);
            acc[mi][ni][v] = 0.f;
          }
      }
    }
    __syncthreads();
  }

#pragma unroll
  for (int mi = 0; mi < 4; ++mi)
#pragma unroll
    for (int ni = 0; ni < 4; ++ni)
#pragma unroll
      for (int v = 0; v < 4; ++v) {
        int row = s0 + wm * 64 + mi * 16 + q * 4 + v;
        int col = o0 + wn * 64 + ni * 16 + lane15;
        atomicAdd(&out[row * OO + col], oacc[mi][ni][v]);
      }
}

extern "C" void kernel_launch(void* const* d_in, const int* in_sizes, int n_in,
                              void* d_out, int out_size, void* d_ws, size_t ws_size,
                              hipStream_t stream) {
  const float* X = (const float*)d_in[0];
  const float* W = (const float*)d_in[1];
  const float* b = (const float*)d_in[2];
  const float* lam = (const float*)d_in[3];
  float* out = (float*)d_out;

  // ws layout: Xq 8MB | Wq 8MB | sX 32KB | sW 32KB
  const size_t qbytes = (size_t)SS * DD;
  const size_t need = 2 * qbytes + 2 * (size_t)SS * sizeof(float);
  if (ws_size >= need) {
    char* Xq = (char*)d_ws;
    char* Wq = Xq + qbytes;
    float* sX = (float*)(Wq + qbytes);
    float* sW = sX + SS;
    // 4096 blocks x 4 waves = 16384 rows (X then W)
    somfnn_quant<<<dim3(4096), dim3(256), 0, stream>>>(X, W, Xq, Wq, sX, sW, (float4*)out);
    // R0 grid: 512 blocks = 64 s-tiles x 4 o-tiles x 2 r-halves
    somfnn_gemm_i8<<<dim3(512), dim3(256), 0, stream>>>(Xq, Wq, sX, sW, b, lam, out);
  } else {
    hipMemsetAsync(out, 0, (size_t)SS * OO * sizeof(float), stream);
    somfnn_gemm_fb<<<dim3(512), dim3(256), 0, stream>>>(X, W, b, lam, out);
  }
}

// Round 8
// 207.626 us; speedup vs baseline: 1.6796x; 1.6796x over previous
//
#include <hip/hip_runtime.h>
#include <hip/hip_bf16.h>
#include <stdint.h>

#define SS 8192
#define DD 1024
#define RR 16
#define OO 512

typedef __bf16 bf16_8 __attribute__((ext_vector_type(8)));
typedef float f32_4 __attribute__((ext_vector_type(4)));
typedef int i32_4 __attribute__((ext_vector_type(4)));

typedef __attribute__((address_space(1))) void g1_void;
typedef __attribute__((address_space(3))) void lds_void;

#define L2E 1.44269504f

__device__ __forceinline__ void gload_lds16(const void* g, void* l) {
  __builtin_amdgcn_global_load_lds((g1_void*)(uintptr_t)g,
                                   (lds_void*)(uint32_t)(uintptr_t)l, 16, 0, 0);
}

// Per-row absmax quantization to int8 + zero d_out.
// R7 wave-per-row version (PASSED R2-R7, absmax 0.0625). Byte-identical.
__global__ __launch_bounds__(256) void somfnn_quant(
    const float* __restrict__ X, const float* __restrict__ W,
    char* __restrict__ Xq, char* __restrict__ Wq,
    float* __restrict__ sX, float* __restrict__ sW, float4* __restrict__ out) {
  const int tid = threadIdx.x;
  const int wv = tid >> 6;
  const int l = tid & 63;
  const int r = blockIdx.x * 4 + wv;  // 0..16383; rows 0..8191 = X, rest = W
  const bool isX = r < SS;
  const float* src = isX ? (X + (size_t)r * DD) : (W + (size_t)(r - SS) * DD);
  char* dst = isX ? (Xq + (size_t)r * DD) : (Wq + (size_t)(r - SS) * DD);

  const float4* s4 = (const float4*)src;
  float4 v[4];
#pragma unroll
  for (int c = 0; c < 4; ++c) v[c] = s4[c * 64 + l];

  out[(size_t)blockIdx.x * 256 + tid] = float4{0.f, 0.f, 0.f, 0.f};

  float m = 0.f;
#pragma unroll
  for (int c = 0; c < 4; ++c)
    m = fmaxf(m, fmaxf(fmaxf(fabsf(v[c].x), fabsf(v[c].y)),
                       fmaxf(fabsf(v[c].z), fabsf(v[c].w))));
#pragma unroll
  for (int off = 32; off > 0; off >>= 1) m = fmaxf(m, __shfl_xor(m, off, 64));
  m = fmaxf(m, 1e-20f);

  const float inv = 127.0f / m;
  int* di = (int*)dst;
#pragma unroll
  for (int c = 0; c < 4; ++c) {
    int q0 = __float2int_rn(v[c].x * inv);
    int q1 = __float2int_rn(v[c].y * inv);
    int q2 = __float2int_rn(v[c].z * inv);
    int q3 = __float2int_rn(v[c].w * inv);
    di[c * 64 + l] = (q0 & 0xff) | ((q1 & 0xff) << 8) | ((q2 & 0xff) << 16) |
                     ((q3 & 0xff) << 24);
  }
  if (l == 0) {
    if (isX) sX[r] = m / 127.0f;
    else sW[r - SS] = m / 127.0f;
  }
}

// i8 GEMM. R13: 8-WAVE PHASE-SPLIT SCHEDULE (guide T3+T4+T5 port).
// Model recalibration (R7 post-mortem): one 16x16x64 i8 MFMA holds its
// SIMD's matrix pipe ~20.5 cyc -> R0's step = 1311 cyc MFMA (34%, matches
// MfmaUtil) + ~1536-2260 cyc LDS + ~1260 VALU, all comparable: the loss is
// cross-pipe overlap, exactly what the phased schedule fixes (m196/m218:
// counted-vmcnt 8-phase = +28..41% and is NULL at 2-phase -> R9 failed).
// Structure: block 256x128, 512 thr / 8 waves (4M x 2N, wave 64x64, acc 64
// + oacc 64 regs - the proven budget), BK=64, swizzle formulas copied
// VERBATIM from the numerically-verified R3/R9/R10/R11 kernels (bank
// conflicts measured 0; R12's improvised map measured 8.4M - lesson).
// 3 LDS buffers (91 KB, 1 block/CU, grid exactly 256 = 32s x 4o x 2rh).
// Per step t (buf t%3): 2 phases, each {ds_read half the frags | issue 1-2
// gloads for t+2 -> buf (t+2)%3 ; lgkmcnt(0); setprio(1); 8 MFMA;
// setprio(0); barrier}. End of step: vmcnt(3) - drains the 3 loads for t+1
// issued a FULL step earlier (cheap), keeps this step's 3 in flight across
// the barrier. Never vmcnt(0) mid-loop. Counts exact: loop VMEM = exactly
// 3 gloads/step/wave. 3-buf safety: t reads t%3; DMA for t+2 writes
// (t+2)%3 != t%3,(t+1)%3; end-of-(t+1) vmcnt(3) drains t+2's loads before
// any wave crosses into t+2.
__global__ __launch_bounds__(512, 2) void somfnn_gemm_i8(
    const char* __restrict__ Xq, const char* __restrict__ Wq,
    const float* __restrict__ sX, const float* __restrict__ sW,
    const float* __restrict__ bias_g, const float* __restrict__ lam_g,
    float* __restrict__ out) {
  constexpr int BM = 256, BN = 128, BK = 64;
  constexpr int NSTEP = 8 * (DD / BK);  // 8 rules * 16 k-tiles = 128

  __shared__ __align__(16) char lds_a[3][BM * BK];  // 48 KB
  __shared__ __align__(16) char lds_b[3][BN * BK];  // 24 KB
  __shared__ float lds_bias[8 * BN];   // 4 KB
  __shared__ float lds_sB[8 * BN];     // 4 KB
  __shared__ float lds_lam[8 * BM];    // 8 KB
  __shared__ float lds_sA[BM];         // 1 KB

  const int tid = threadIdx.x;
  const int bid = blockIdx.x;

  const int l = tid & 63;
  const int w = tid >> 6;        // 0..7
  const int lane15 = l & 15;
  const int q = l >> 4;
  const int wm = w >> 1;         // 0..3 : M wave coord (64 rows each)
  const int wn = w & 1;          // 0..1 : N wave coord (64 cols each)

  // XCD swizzle: xcd owns 4 s-tiles (4*256 rows = 1 MB A, L2-resident)
  const int xcd = bid & 7;
  const int chunk = bid >> 3;             // [0,32)
  const int sb = xcd * 4 + (chunk & 3);   // [0,32)
  const int ob = (chunk >> 2) & 3;
  const int rhalf = chunk >> 4;
  const int s0 = sb * BM;
  const int o0 = ob * BN;
  const int r0 = rhalf * 8;

  for (int idx = tid; idx < 8 * BN; idx += 512) {
    int rr = idx >> 7, j = idx & 127;
    lds_bias[idx] = -L2E * bias_g[(r0 + rr) * OO + o0 + j];
    lds_sB[idx] = sW[(r0 + rr) * OO + o0 + j];
  }
  for (int idx = tid; idx < 8 * BM; idx += 512) {
    int rr = idx >> 8, i = idx & 255;
    lds_lam[idx] = lam_g[(s0 + i) * RR + (r0 + rr)];
  }
  if (tid < BM) lds_sA[tid] = sX[s0 + tid];

  // Staging offsets — swizzle formula VERBATIM from R3 (bank-verified 0):
  // chunk cc -> row = cc>>2, kc = (cc&3) ^ ((row>>1)&3); LDS stays linear.
  // A tile 256x64 = 1024 chunks: wave w writes cc = w*128 + g*64 + l (g=0,1)
  // B tile 128x64 = 512 chunks:  wave w writes cc = w*64 + l
  int aoff[2];
#pragma unroll
  for (int g = 0; g < 2; ++g) {
    int cc = w * 128 + g * 64 + l;
    int row = cc >> 2;
    int kc = (cc & 3) ^ ((row >> 1) & 3);
    aoff[g] = row * DD + kc * 16;
  }
  int boff;
  {
    int cc = w * 64 + l;
    int row = cc >> 2;
    int kc = (cc & 3) ^ ((row >> 1) & 3);
    boff = row * DD + kc * 16;
  }

  // Fragment offsets (VERBATIM formula from R3): byte = r*64 + (q^((r>>1)&3))*16
  int afo[4], bfo[4];
#pragma unroll
  for (int t = 0; t < 4; ++t) {
    int ra = wm * 64 + t * 16 + lane15;
    afo[t] = ra * BK + ((q ^ ((ra >> 1) & 3)) * 16);
    int rb = wn * 64 + t * 16 + lane15;
    bfo[t] = rb * BK + ((q ^ ((rb >> 1) & 3)) * 16);
  }

  const char* gA = Xq + (size_t)s0 * DD;
  const char* gB = Wq + ((size_t)r0 * OO + o0) * DD;

  auto issueA = [&](int step, int buf) {
    int rl = step >> 4, kt = step & 15;
    (void)rl;
    const char* ga = gA + kt * BK;
    gload_lds16(ga + aoff[0], &lds_a[buf][w * 2048]);
    gload_lds16(ga + aoff[1], &lds_a[buf][w * 2048 + 1024]);
  };
  auto issueB = [&](int step, int buf) {
    int rl = step >> 4, kt = step & 15;
    const char* gb = gB + (size_t)rl * OO * DD + kt * BK;
    gload_lds16(gb + boff, &lds_b[buf][w * 1024]);
  };

  i32_4 acc[4][4];
  f32_4 oacc[4][4];
#pragma unroll
  for (int mi = 0; mi < 4; ++mi)
#pragma unroll
    for (int ni = 0; ni < 4; ++ni) {
      acc[mi][ni] = i32_4{0, 0, 0, 0};
      oacc[mi][ni] = f32_4{0.f, 0.f, 0.f, 0.f};
    }

  // prologue: prefetch steps 0 and 1; drain step 0 only, then converge
  issueA(0, 0); issueB(0, 0);
  issueA(1, 1); issueB(1, 1);
  asm volatile("s_waitcnt vmcnt(3) lgkmcnt(0)" ::: "memory");
  __builtin_amdgcn_sched_barrier(0);
  __builtin_amdgcn_s_barrier();
  __builtin_amdgcn_sched_barrier(0);

  for (int step = 0; step < NSTEP; ++step) {
    const int cur = step % 3;
    const int nxt = (step + 2) % 3;
    const bool pre = (step + 2) < NSTEP;

    const char* A = lds_a[cur];
    const char* B = lds_b[cur];
    i32_4 av[4], bv[4];

    // ---- phase 0: B frags + A frags 0,1 ; issue A-gloads for step+2 ----
    av[0] = *(const i32_4*)(A + afo[0]);
    av[1] = *(const i32_4*)(A + afo[1]);
#pragma unroll
    for (int ni = 0; ni < 4; ++ni) bv[ni] = *(const i32_4*)(B + bfo[ni]);
    if (pre) issueA(step + 2, nxt);
    asm volatile("s_waitcnt lgkmcnt(0)" ::: "memory");
    __builtin_amdgcn_sched_barrier(0);
    __builtin_amdgcn_s_setprio(1);
#pragma unroll
    for (int ni = 0; ni < 4; ++ni)
      acc[0][ni] = __builtin_amdgcn_mfma_i32_16x16x64_i8(av[0], bv[ni], acc[0][ni], 0, 0, 0);
#pragma unroll
    for (int ni = 0; ni < 4; ++ni)
      acc[1][ni] = __builtin_amdgcn_mfma_i32_16x16x64_i8(av[1], bv[ni], acc[1][ni], 0, 0, 0);
    __builtin_amdgcn_s_setprio(0);
    __builtin_amdgcn_sched_barrier(0);
    __builtin_amdgcn_s_barrier();
    __builtin_amdgcn_sched_barrier(0);

    // ---- phase 1: A frags 2,3 ; issue B-gload for step+2 ----
    av[2] = *(const i32_4*)(A + afo[2]);
    av[3] = *(const i32_4*)(A + afo[3]);
    if (pre) issueB(step + 2, nxt);
    asm volatile("s_waitcnt lgkmcnt(0)" ::: "memory");
    __builtin_amdgcn_sched_barrier(0);
    __builtin_amdgcn_s_setprio(1);
#pragma unroll
    for (int ni = 0; ni < 4; ++ni)
      acc[2][ni] = __builtin_amdgcn_mfma_i32_16x16x64_i8(av[2], bv[ni], acc[2][ni], 0, 0, 0);
#pragma unroll
    for (int ni = 0; ni < 4; ++ni)
      acc[3][ni] = __builtin_amdgcn_mfma_i32_16x16x64_i8(av[3], bv[ni], acc[3][ni], 0, 0, 0);
    __builtin_amdgcn_s_setprio(0);

    if ((step & 15) == 15) {  // rule finished K: dequant + sigmoid + reduce
      const int rl = step >> 4;
      float lsa[4][4], lamv[4][4];
#pragma unroll
      for (int mi = 0; mi < 4; ++mi)
#pragma unroll
        for (int v = 0; v < 4; ++v) {
          int ridx = wm * 64 + mi * 16 + q * 4 + v;
          lsa[mi][v] = -L2E * lds_sA[ridx];
          lamv[mi][v] = lds_lam[rl * BM + ridx];
        }
#pragma unroll
      for (int ni = 0; ni < 4; ++ni) {
        const int cidx = wn * 64 + ni * 16 + lane15;
        const float nb = lds_bias[rl * BN + cidx];
        const float sbv = lds_sB[rl * BN + cidx];
#pragma unroll
        for (int mi = 0; mi < 4; ++mi)
#pragma unroll
          for (int v = 0; v < 4; ++v) {
            float t = __builtin_fmaf((float)acc[mi][ni][v], lsa[mi][v] * sbv, nb);
            float e = __builtin_amdgcn_exp2f(t);
            float h = __builtin_amdgcn_rcpf(1.0f + e);
            oacc[mi][ni][v] = __builtin_fmaf(lamv[mi][v], h, oacc[mi][ni][v]);
            acc[mi][ni][v] = 0;
          }
      }
    }

    // end-of-step: counted drain (loads for step+1 were issued during
    // step-1, a full step ago). Tail: step+2 gone -> drain everything.
    if (pre) {
      asm volatile("s_waitcnt vmcnt(3)" ::: "memory");
    } else if (step + 1 < NSTEP) {
      asm volatile("s_waitcnt vmcnt(0)" ::: "memory");
    }
    __builtin_amdgcn_sched_barrier(0);
    __builtin_amdgcn_s_barrier();
    __builtin_amdgcn_sched_barrier(0);
  }

#pragma unroll
  for (int mi = 0; mi < 4; ++mi)
#pragma unroll
    for (int ni = 0; ni < 4; ++ni)
#pragma unroll
      for (int v = 0; v < 4; ++v) {
        int row = s0 + wm * 64 + mi * 16 + q * 4 + v;
        int col = o0 + wn * 64 + ni * 16 + lane15;
        atomicAdd(&out[row * OO + col], oacc[mi][ni][v]);
      }
}

// Fallback (ws too small): bf16 GEMM converting fp32 during LDS staging.
__global__ __launch_bounds__(256, 2) void somfnn_gemm_fb(
    const float* __restrict__ Xf32, const float* __restrict__ Wf32,
    const float* __restrict__ bias_g, const float* __restrict__ lam_g,
    float* __restrict__ out) {
  constexpr int BM = 128, BN = 128, BK = 64;
  constexpr int TILE = BM * BK;
  constexpr int NSTEP = 8 * (DD / BK);

  __shared__ __align__(16) __bf16 lds_a[2][TILE];
  __shared__ __align__(16) __bf16 lds_b[2][TILE];
  __shared__ float lds_bias[8 * BN];
  __shared__ float lds_lam[8 * BM];

  const int tid = threadIdx.x;
  const int bid = blockIdx.x;
  const int l = tid & 63;
  const int w = tid >> 6;
  const int lane15 = l & 15;
  const int q = l >> 4;
  const int wm = w >> 1;
  const int wn = w & 1;

  const int xcd = bid & 7;
  const int chunk = bid >> 3;
  const int sb = xcd * 8 + (chunk & 7);
  const int ob = (chunk >> 3) & 3;
  const int rhalf = chunk >> 5;
  const int s0 = sb * BM;
  const int o0 = ob * BN;
  const int r0 = rhalf * 8;

  for (int idx = tid; idx < 8 * BN; idx += 256) {
    int rr = idx >> 7, j = idx & 127;
    lds_bias[idx] = -L2E * bias_g[(r0 + rr) * OO + o0 + j];
  }
  for (int idx = tid; idx < 8 * BM; idx += 256) {
    int rr = idx >> 7, i = idx & 127;
    lds_lam[idx] = lam_g[(s0 + i) * RR + (r0 + rr)];
  }

  int goffs[4], coffs[4];
#pragma unroll
  for (int i = 0; i < 4; ++i) {
    int c = (w * 4 + i) * 64 + l;
    int row = c >> 3;
    int k8 = (c & 7) ^ (row & 7);
    goffs[i] = row * DD + k8 * 8;
    coffs[i] = c * 8;
  }
  int afo[4], bfo[4];
#pragma unroll
  for (int t = 0; t < 4; ++t) {
    int ra = wm * 64 + t * 16 + lane15;
    afo[t] = (ra * 8 + (q ^ (ra & 7))) * 8;
    int rb = wn * 64 + t * 16 + lane15;
    bfo[t] = (rb * 8 + (q ^ (rb & 7))) * 8;
  }

  float4 ra_[4][2], rb_[4][2];
  auto issue_fb = [&](int step) {
    int rl = step >> 4, kt = step & 15;
    const float* ga = Xf32 + s0 * DD + kt * BK;
    const float* gb = Wf32 + ((r0 + rl) * OO + o0) * DD + kt * BK;
#pragma unroll
    for (int i = 0; i < 4; ++i) {
      const float4* p = (const float4*)(ga + goffs[i]);
      ra_[i][0] = p[0]; ra_[i][1] = p[1];
      const float4* pb = (const float4*)(gb + goffs[i]);
      rb_[i][0] = pb[0]; rb_[i][1] = pb[1];
    }
  };
  auto commit_fb = [&](int buf) {
#pragma unroll
    for (int i = 0; i < 4; ++i) {
      bf16_8 t;
      t[0] = (__bf16)ra_[i][0].x; t[1] = (__bf16)ra_[i][0].y;
      t[2] = (__bf16)ra_[i][0].z; t[3] = (__bf16)ra_[i][0].w;
      t[4] = (__bf16)ra_[i][1].x; t[5] = (__bf16)ra_[i][1].y;
      t[6] = (__bf16)ra_[i][1].z; t[7] = (__bf16)ra_[i][1].w;
      *(bf16_8*)&lds_a[buf][coffs[i]] = t;
      bf16_8 u;
      u[0] = (__bf16)rb_[i][0].x; u[1] = (__bf16)rb_[i][0].y;
      u[2] = (__bf16)rb_[i][0].z; u[3] = (__bf16)rb_[i][0].w;
      u[4] = (__bf16)rb_[i][1].x; u[5] = (__bf16)rb_[i][1].y;
      u[6] = (__bf16)rb_[i][1].z; u[7] = (__bf16)rb_[i][1].w;
      *(bf16_8*)&lds_b[buf][coffs[i]] = u;
    }
  };

  f32_4 acc[4][4], oacc[4][4];
#pragma unroll
  for (int mi = 0; mi < 4; ++mi)
#pragma unroll
    for (int ni = 0; ni < 4; ++ni) {
      acc[mi][ni] = f32_4{0.f, 0.f, 0.f, 0.f};
      oacc[mi][ni] = f32_4{0.f, 0.f, 0.f, 0.f};
    }

  issue_fb(0);
  commit_fb(0);
  __syncthreads();

  for (int step = 0; step < NSTEP; ++step) {
    const int cur = step & 1;
    const bool more = (step + 1) < NSTEP;
    if (more) issue_fb(step + 1);

    const __bf16* A = lds_a[cur];
    const __bf16* B = lds_b[cur];
#pragma unroll
    for (int ks = 0; ks < 2; ++ks) {
      const int xr = ks ? 32 : 0;
      bf16_8 av[4], bv[4];
#pragma unroll
      for (int mi = 0; mi < 4; ++mi) av[mi] = *(const bf16_8*)(A + (afo[mi] ^ xr));
#pragma unroll
      for (int ni = 0; ni < 4; ++ni) bv[ni] = *(const bf16_8*)(B + (bfo[ni] ^ xr));
#pragma unroll
      for (int mi = 0; mi < 4; ++mi)
#pragma unroll
        for (int ni = 0; ni < 4; ++ni)
          acc[mi][ni] =
              __builtin_amdgcn_mfma_f32_16x16x32_bf16(av[mi], bv[ni], acc[mi][ni], 0, 0, 0);
    }
    if (more) commit_fb(cur ^ 1);

    if ((step & 15) == 15) {
      const int rl = step >> 4;
      float lamv[4][4];
#pragma unroll
      for (int mi = 0; mi < 4; ++mi)
#pragma unroll
        for (int v = 0; v < 4; ++v)
          lamv[mi][v] = lds_lam[rl * BM + wm * 64 + mi * 16 + q * 4 + v];
#pragma unroll
      for (int ni = 0; ni < 4; ++ni) {
        const float nb = lds_bias[rl * BN + wn * 64 + ni * 16 + lane15];
#pragma unroll
        for (int mi = 0; mi < 4; ++mi)
#pragma unroll
          for (int v = 0; v < 4; ++v) {
            float t = __builtin_fmaf(acc[mi][ni][v], -L2E, nb);
            float e = __builtin_amdgcn_exp2f(t);
            float h = __builtin_amdgcn_rcpf(1.0f + e);
            oacc[mi][ni][v] = __builtin_fmaf(lamv[mi][v], h, oacc[mi][ni][v]);
            acc[mi][ni][v] = 0.f;
          }
      }
    }
    __syncthreads();
  }

#pragma unroll
  for (int mi = 0; mi < 4; ++mi)
#pragma unroll
    for (int ni = 0; ni < 4; ++ni)
#pragma unroll
      for (int v = 0; v < 4; ++v) {
        int row = s0 + wm * 64 + mi * 16 + q * 4 + v;
        int col = o0 + wn * 64 + ni * 16 + lane15;
        atomicAdd(&out[row * OO + col], oacc[mi][ni][v]);
      }
}

extern "C" void kernel_launch(void* const* d_in, const int* in_sizes, int n_in,
                              void* d_out, int out_size, void* d_ws, size_t ws_size,
                              hipStream_t stream) {
  const float* X = (const float*)d_in[0];
  const float* W = (const float*)d_in[1];
  const float* b = (const float*)d_in[2];
  const float* lam = (const float*)d_in[3];
  float* out = (float*)d_out;

  // ws layout: Xq 8MB | Wq 8MB | sX 32KB | sW 32KB
  const size_t qbytes = (size_t)SS * DD;
  const size_t need = 2 * qbytes + 2 * (size_t)SS * sizeof(float);
  if (ws_size >= need) {
    char* Xq = (char*)d_ws;
    char* Wq = Xq + qbytes;
    float* sX = (float*)(Wq + qbytes);
    float* sW = sX + SS;
    somfnn_quant<<<dim3(4096), dim3(256), 0, stream>>>(X, W, Xq, Wq, sX, sW, (float4*)out);
    // 256 blocks x 512 threads: 32 s-tiles(256) x 4 o-tiles(128) x 2 r-halves
    somfnn_gemm_i8<<<dim3(256), dim3(512), 0, stream>>>(Xq, Wq, sX, sW, b, lam, out);
  } else {
    hipMemsetAsync(out, 0, (size_t)SS * OO * sizeof(float), stream);
    somfnn_gemm_fb<<<dim3(512), dim3(256), 0, stream>>>(X, W, b, lam, out);
  }
}